// Round 11
// baseline (259.868 us; speedup 1.0000x reference)
//
#include <hip/hip_runtime.h>

typedef float f32x4  __attribute__((ext_vector_type(4)));
typedef short bf16x8 __attribute__((ext_vector_type(8)));

#define SEQT 512
#define TC   16
#define NCH  (SEQT/TC)
#define ROWDW 68              // dwords per batch-row per buffer (16 steps * 4 + 4 pad)
#define BUFDW (16*ROWDW)

#define FEXP2(v) __builtin_amdgcn_exp2f(v)
#define FRCP(v)  __builtin_amdgcn_rcpf(v)
__device__ __forceinline__ unsigned pkbf(float a, float b){ unsigned r; asm("v_cvt_pk_bf16_f32 %0, %1, %2":"=v"(r):"v"(a),"v"(b)); return r; }
__device__ __forceinline__ float sigm (float s){ return FRCP(1.0f + FEXP2(s * -1.4426950408889634f)); }

// lanes<32 receive lane+32's value of v. Early-clobber outputs guarantee
// distinct registers (R10's "+v","+v" same-value form could coalesce into a
// self-referential swap -> undefined data).
__device__ __forceinline__ unsigned swap_hi32(float v){
    unsigned dst, src;
    asm("v_mov_b32 %0, %2\n\t"
        "v_mov_b32 %1, %2\n\t"
        "v_permlane32_swap_b32 %0, %1"
        : "=&v"(dst), "=&v"(src)
        : "v"(__float_as_uint(v)));
    return src;
}

union FragU { unsigned u[4]; bf16x8 v; uint4 q; };

// Unit-to-cell map (cell = lane-group cg, tile t):
//   g0:{u0,u1,-}  g1:{u4,u5,u6}  g2:{u2,u3,-}  g3:{u9,u8,u7}
__device__ __forceinline__ int unit_of(int cg, int t){
    if (t==0) return cg==0 ? 0 : cg==1 ? 4 : cg==2 ? 2 : 9;
    if (t==1) return cg==0 ? 1 : cg==1 ? 5 : cg==2 ? 3 : 8;
    return      cg==0 ? -1 : cg==1 ? 6 : cg==2 ? -1 : 7;
}
// K-slot -> z-component (z = [x0..x5, h0..h9]); -1 = zero padding.
__device__ __forceinline__ int zslot(int k){
    if (k < 6)  return k;
    if (k == 6) return 6;
    if (k == 7) return 7;
    if (k == 8) return 10;
    if (k == 9) return 11;
    if (k == 10) return 12;
    if (k == 11) return 13;
    if (k == 16) return 8;
    if (k == 17) return 9;
    if (k == 24) return 15;
    if (k == 25) return 14;
    return -1;
}

// LSTM cell, 7 trans (5 exp + 2 rcp) — R9's proven formula:
//   P=(1+Ei)(1+Eg), Q=1+Ef, r=rcp(P*Q):  sigma(f)=P*r,  i*g=(1-Eg)*Q*r
//   h = o*tanh(c) = (1-Ec)/[(1+Eo)(1+Ec)]
__device__ __forceinline__ void cell(const f32x4 a, float& c, float& h){
    const float K1 = -1.4426950408889634f;   // -log2(e)
    const float K2 = -2.8853900817779268f;   // -2*log2(e)
    float Ei = FEXP2(a[0]*K1);
    float Ef = FEXP2(a[1]*K1);
    float Eg = FEXP2(a[2]*K2);
    float Eo = FEXP2(a[3]*K1);
    float P  = (1.0f+Ei)*(1.0f+Eg);
    float Q  = 1.0f+Ef;
    float r  = FRCP(P*Q);
    float ig = (1.0f-Eg)*Q*r;
    float sf = P*r;
    c = fmaf(sf, c, ig);
    float Ec  = FEXP2(c*K2);
    float roc = FRCP((1.0f+Eo)*(1.0f+Ec));
    h = (1.0f-Ec)*roc;
}

__global__ __launch_bounds__(256)
__attribute__((amdgpu_waves_per_eu(1, 1)))
void Model_88459146428723_kernel(const float* __restrict__ x,
                                 const float* __restrict__ Wih,
                                 const float* __restrict__ Whh,
                                 const float* __restrict__ bih,
                                 const float* __restrict__ bhh,
                                 const float* __restrict__ Wfc,
                                 const float* __restrict__ bfc,
                                 float* __restrict__ out)
{
    __shared__ unsigned xbf[4][2*BUFDW];     // per-wave private double-buffered x
    __shared__ float hfin[4][16][12];

    const int tid = threadIdx.x;
    const int wv = tid >> 6, l = tid & 63, m = l & 15, gq = l >> 4;

    // ---- A fragments: lane holds A-row (l&15), k = 8*(l>>4)+j ----
    FragU wf[3];
    #pragma unroll
    for (int t=0; t<3; ++t){
        const int u  = unit_of(m>>2, t);
        const int gt = m & 3;
        float av[8];
        #pragma unroll
        for (int j=0; j<8; ++j){
            const int z = zslot(8*gq + j);
            float v = 0.0f;
            if (u >= 0 && z >= 0){
                const int row = gt*10 + u;
                v = (z < 6) ? Wih[row*6 + z] : Whh[row*10 + (z-6)];
            }
            av[j] = v;
        }
        #pragma unroll
        for (int w=0; w<4; ++w) wf[t].u[w] = pkbf(av[2*w], av[2*w+1]);
    }
    // ---- bias as MFMA C-seed (same for both groups) ----
    f32x4 bias[3];
    #pragma unroll
    for (int t=0; t<3; ++t){
        const int u = unit_of(gq, t);
        #pragma unroll
        for (int jD=0; jD<4; ++jD)
            bias[t][jD] = (u>=0) ? (bih[jD*10+u] + bhh[jD*10+u]) : 0.0f;
    }

    // ---- x staging: global f32 -> LDS bf16-pair words ----
    const float* xwb = x + (size_t)(blockIdx.x*64 + wv*16) * (SEQT*6);
    unsigned* myx = &xbf[wv][0];
    float4 stg[6];

    auto load_ch = [&](int ch){
        #pragma unroll
        for (int k=0; k<6; ++k){
            const int f = l + 64*k, mb = f/24, c4 = f%24;
            stg[k] = *reinterpret_cast<const float4*>(xwb + (size_t)mb*(SEQT*6) + ch*(TC*6) + c4*4);
        }
    };
    auto write_buf = [&](int buf){
        unsigned* dst = myx + buf*BUFDW;
        #pragma unroll
        for (int k=0; k<6; ++k){
            const int f = l + 64*k, mb = f/24, c4 = f%24;
            const int P0 = 2*c4, P1 = P0+1;
            dst[mb*ROWDW + (P0/3)*4 + (P0%3)] = pkbf(stg[k].x, stg[k].y);
            dst[mb*ROWDW + (P1/3)*4 + (P1%3)] = pkbf(stg[k].z, stg[k].w);
        }
    };

    load_ch(0); write_buf(0);

    const int mA = m & 7;          // group A batch row (cols 8-15 duplicate 0-7)
    const int mB = 8 + (m & 7);    // group B batch row
    uint4 xwA = *reinterpret_cast<const uint4*>(myx + mA*ROWDW);
    uint4 xwB = *reinterpret_cast<const uint4*>(myx + mB*ROWDW);

    const bool is_g0 = (gq==0), is_g1 = (gq==1);

    unsigned A0  = is_g0 ? xwA.x : 0u, A1  = is_g0 ? xwA.y : 0u, A2  = is_g0 ? xwA.z : 0u, A3  = 0u;
    unsigned Bb0 = is_g0 ? xwB.x : 0u, Bb1 = is_g0 ? xwB.y : 0u, Bb2 = is_g0 ? xwB.z : 0u, Bb3 = 0u;
    float cA0=0.f, cA1=0.f, cA2=0.f, hA0=0.f, hA1=0.f, hA2=0.f;
    float cB0=0.f, cB1=0.f, cB2=0.f, hB0=0.f, hB1=0.f, hB2=0.f;

    #pragma unroll 1
    for (int ch=0; ch<NCH; ++ch){
        const int cur = ch & 1;
        if (ch+1 < NCH) load_ch(ch+1);
        const unsigned* aA = myx + cur*BUFDW + mA*ROWDW;
        const unsigned* aB = myx + cur*BUFDW + mB*ROWDW;
        const unsigned* bA = myx + (cur^1)*BUFDW + mA*ROWDW;
        const unsigned* bB = myx + (cur^1)*BUFDW + mB*ROWDW;

        #pragma unroll
        for (int tt=0; tt<TC; ++tt){
            FragU FA; FA.u[0]=A0;  FA.u[1]=A1;  FA.u[2]=A2;  FA.u[3]=A3;
            FragU FB; FB.u[0]=Bb0; FB.u[1]=Bb1; FB.u[2]=Bb2; FB.u[3]=Bb3;
            f32x4 a0A = __builtin_amdgcn_mfma_f32_16x16x32_bf16(wf[0].v, FA.v, bias[0], 0,0,0);
            f32x4 a1A = __builtin_amdgcn_mfma_f32_16x16x32_bf16(wf[1].v, FA.v, bias[1], 0,0,0);
            f32x4 a2A = __builtin_amdgcn_mfma_f32_16x16x32_bf16(wf[2].v, FA.v, bias[2], 0,0,0);
            f32x4 a0B = __builtin_amdgcn_mfma_f32_16x16x32_bf16(wf[0].v, FB.v, bias[0], 0,0,0);
            f32x4 a1B = __builtin_amdgcn_mfma_f32_16x16x32_bf16(wf[1].v, FB.v, bias[1], 0,0,0);
            f32x4 a2B = __builtin_amdgcn_mfma_f32_16x16x32_bf16(wf[2].v, FB.v, bias[2], 0,0,0);

            // next step's x words early (lgkm wait hides under the cell chains)
            uint4 xwnA, xwnB;
            if (tt < 15){ xwnA = *reinterpret_cast<const uint4*>(aA + (tt+1)*4);
                          xwnB = *reinterpret_cast<const uint4*>(aB + (tt+1)*4); }
            else        { xwnA = *reinterpret_cast<const uint4*>(bA);
                          xwnB = *reinterpret_cast<const uint4*>(bB); }   // stale at last chunk: unused

            // two independent scalar chains (A fills B's latency bubbles)
            cell(a0A, cA0, hA0);
            cell(a0B, cB0, hB0);
            cell(a1A, cA1, hA1);
            cell(a1B, cB1, hB1);
            cell(a2A, cA2, hA2);
            cell(a2B, cB2, hB2);

            if (tt==14 && ch+1<NCH) write_buf(cur^1);

            // ---- routing, group A ----
            {
                const unsigned pA = pkbf(hA0, hA1);
                const unsigned pB = pkbf(hA2, __uint_as_float(swap_hi32(hA2)));
                A0 = is_g0 ? xwnA.x : pA;
                A1 = is_g0 ? xwnA.y : (is_g1 ? pB : 0u);
                A2 = is_g0 ? xwnA.z : 0u;
                A3 = is_g0 ? pA     : 0u;
            }
            // ---- routing, group B ----
            {
                const unsigned pA = pkbf(hB0, hB1);
                const unsigned pB = pkbf(hB2, __uint_as_float(swap_hi32(hB2)));
                Bb0 = is_g0 ? xwnB.x : pA;
                Bb1 = is_g0 ? xwnB.y : (is_g1 ? pB : 0u);
                Bb2 = is_g0 ? xwnB.z : 0u;
                Bb3 = is_g0 ? pA     : 0u;
            }
        }
    }

    // ---- final FC + sigmoid: lanes m<8 write both groups' batches ----
    if (m < 8){
        const int ua = unit_of(gq,0);
        const int ub = unit_of(gq,1);
        const int uc = unit_of(gq,2);
        hfin[wv][m][ua]   = hA0;  hfin[wv][m+8][ua]   = hB0;
        hfin[wv][m][ub]   = hA1;  hfin[wv][m+8][ub]   = hB1;
        if (uc>=0){ hfin[wv][m][uc] = hA2; hfin[wv][m+8][uc] = hB2; }
    }
    __syncthreads();
    if (l < 32){
        const int j = l >> 4, mm = l & 15;
        float a = bfc[j];
        #pragma unroll
        for (int u=0; u<10; ++u) a = fmaf(Wfc[j*10+u], hfin[wv][mm][u], a);
        out[(size_t)(blockIdx.x*64 + wv*16 + mm)*2 + j] = sigm(a);
    }
}

extern "C" void kernel_launch(void* const* d_in, const int* in_sizes, int n_in,
                              void* d_out, int out_size, void* d_ws, size_t ws_size,
                              hipStream_t stream) {
    const float* x   = (const float*)d_in[0];
    const float* Wih = (const float*)d_in[1];
    const float* Whh = (const float*)d_in[2];
    const float* bih = (const float*)d_in[3];
    const float* bhh = (const float*)d_in[4];
    const float* Wfc = (const float*)d_in[5];
    const float* bfc = (const float*)d_in[6];
    float* out = (float*)d_out;

    dim3 grid(16384 / 64);    // 256 blocks x 4 waves = 1024 waves -> 1/SIMD; 2x8 batches/wave
    dim3 block(256);
    Model_88459146428723_kernel<<<grid, block, 0, stream>>>(x, Wih, Whh, bih, bhh, Wfc, bfc, out);
}

// Round 12
// 180.433 us; speedup vs baseline: 1.4402x; 1.4402x over previous
//
#include <hip/hip_runtime.h>

typedef float f32x4  __attribute__((ext_vector_type(4)));
typedef short bf16x8 __attribute__((ext_vector_type(8)));

#define SEQT 512
#define TC   16
#define NCH  (SEQT/TC)
#define ROWDW 68              // dwords per batch-row per buffer (16 steps * 4 + 4 pad)
#define BUFDW (16*ROWDW)

#define FEXP2(v) __builtin_amdgcn_exp2f(v)
#define FRCP(v)  __builtin_amdgcn_rcpf(v)
__device__ __forceinline__ unsigned pkbf(float a, float b){ unsigned r; asm("v_cvt_pk_bf16_f32 %0, %1, %2":"=v"(r):"v"(a),"v"(b)); return r; }
__device__ __forceinline__ float sigm (float s){ return FRCP(1.0f + FEXP2(s * -1.4426950408889634f)); }

// lanes<32 receive lane+32's value of v (hardened: distinct regs guaranteed)
__device__ __forceinline__ unsigned swap_hi32(float v){
    unsigned dst, src;
    asm("v_mov_b32 %0, %2\n\t"
        "v_mov_b32 %1, %2\n\t"
        "v_permlane32_swap_b32 %0, %1"
        : "=&v"(dst), "=&v"(src)
        : "v"(__float_as_uint(v)));
    return src;
}

union FragU { unsigned u[4]; bf16x8 v; uint4 q; };

// Unit-to-cell map (cell = lane-group cg, tile t):
//   g0:{u0,u1,-}  g1:{u4,u5,u6}  g2:{u2,u3,-}  g3:{u9,u8,u7}
__device__ __forceinline__ int unit_of(int cg, int t){
    if (t==0) return cg==0 ? 0 : cg==1 ? 4 : cg==2 ? 2 : 9;
    if (t==1) return cg==0 ? 1 : cg==1 ? 5 : cg==2 ? 3 : 8;
    return      cg==0 ? -1 : cg==1 ? 6 : cg==2 ? -1 : 7;
}
// K-slot -> z-component (z = [x0..x5, h0..h9]); -1 = zero padding.
__device__ __forceinline__ int zslot(int k){
    if (k < 6)  return k;
    if (k == 6) return 6;
    if (k == 7) return 7;
    if (k == 8) return 10;
    if (k == 9) return 11;
    if (k == 10) return 12;
    if (k == 11) return 13;
    if (k == 16) return 8;
    if (k == 17) return 9;
    if (k == 24) return 15;
    if (k == 25) return 14;
    return -1;
}

// LSTM cell, 6 trans (4 exp + 2 rcp), tail shortened to ONE trans level on the
// c->h path via clamped Pade(7,6) tanh (err <1.4e-4 on the clamp, exact f32
// coeffs). Sigmoid denominators merged into ONE rcp:
//   D = pi*pg*pf*po, r = rcp(D):
//     sigma(f) = pi*pg*po * r ; i*g = (1-Eg)*pf*po * r ; sigma(o) = pi*pg*pf * r
__device__ __forceinline__ void cell(const f32x4 a, float& c, float& h){
    const float K1 = -1.4426950408889634f;   // -log2(e)
    const float K2 = -2.8853900817779268f;   // -2*log2(e)
    float Ei = FEXP2(a[0]*K1);
    float Ef = FEXP2(a[1]*K1);
    float Eg = FEXP2(a[2]*K2);
    float Eo = FEXP2(a[3]*K1);
    float pi = 1.0f+Ei, pf = 1.0f+Ef, pg = 1.0f+Eg, po = 1.0f+Eo;
    float T_ig  = pi*pg;
    float T_igo = T_ig*po;
    float T_igf = T_ig*pf;
    float T_fo  = pf*po;
    float D     = T_igo*pf;
    float r  = FRCP(D);
    float sf = T_igo*r;
    float ig = (1.0f-Eg)*T_fo*r;
    float so = T_igf*r;
    c = fmaf(sf, c, ig);
    // tanh(c) via clamped Pade(7,6): x(135135+17325x^2+378x^4+x^6) /
    //                                 (135135+62370x^2+3150x^4+28x^6)
    float cc  = fminf(fmaxf(c, -5.0f), 5.0f);
    float x2  = cc*cc;
    float num = fmaf(x2, fmaf(x2, (x2+378.0f), 17325.0f), 135135.0f);
    float den = fmaf(x2, fmaf(x2, fmaf(x2, 28.0f, 3150.0f), 62370.0f), 135135.0f);
    h = so * (cc*num) * FRCP(den);
}

__global__ __launch_bounds__(256)
__attribute__((amdgpu_waves_per_eu(1, 1)))
void Model_88459146428723_kernel(const float* __restrict__ x,
                                 const float* __restrict__ Wih,
                                 const float* __restrict__ Whh,
                                 const float* __restrict__ bih,
                                 const float* __restrict__ bhh,
                                 const float* __restrict__ Wfc,
                                 const float* __restrict__ bfc,
                                 float* __restrict__ out)
{
    __shared__ unsigned xbf[4][2*BUFDW];     // per-wave private double-buffered x
    __shared__ float hfin[4][16][12];

    const int tid = threadIdx.x;
    const int wv = tid >> 6, l = tid & 63, m = l & 15, gq = l >> 4;

    // ---- A fragments: lane holds A-row (l&15), k = 8*(l>>4)+j ----
    FragU wf[3];
    #pragma unroll
    for (int t=0; t<3; ++t){
        const int u  = unit_of(m>>2, t);
        const int gt = m & 3;
        float av[8];
        #pragma unroll
        for (int j=0; j<8; ++j){
            const int z = zslot(8*gq + j);
            float v = 0.0f;
            if (u >= 0 && z >= 0){
                const int row = gt*10 + u;
                v = (z < 6) ? Wih[row*6 + z] : Whh[row*10 + (z-6)];
            }
            av[j] = v;
        }
        #pragma unroll
        for (int w=0; w<4; ++w) wf[t].u[w] = pkbf(av[2*w], av[2*w+1]);
    }
    // ---- bias as MFMA C-seed ----
    f32x4 bias[3];
    #pragma unroll
    for (int t=0; t<3; ++t){
        const int u = unit_of(gq, t);
        #pragma unroll
        for (int jD=0; jD<4; ++jD)
            bias[t][jD] = (u>=0) ? (bih[jD*10+u] + bhh[jD*10+u]) : 0.0f;
    }

    // ---- x staging: global f32 -> LDS bf16-pair words ----
    const float* xwb = x + (size_t)(blockIdx.x*64 + wv*16) * (SEQT*6);
    unsigned* myx = &xbf[wv][0];
    float4 stg[6];

    auto load_ch = [&](int ch){
        #pragma unroll
        for (int k=0; k<6; ++k){
            const int f = l + 64*k, mb = f/24, c4 = f%24;
            stg[k] = *reinterpret_cast<const float4*>(xwb + (size_t)mb*(SEQT*6) + ch*(TC*6) + c4*4);
        }
    };
    auto write_buf = [&](int buf){
        unsigned* dst = myx + buf*BUFDW;
        #pragma unroll
        for (int k=0; k<6; ++k){
            const int f = l + 64*k, mb = f/24, c4 = f%24;
            const int P0 = 2*c4, P1 = P0+1;
            dst[mb*ROWDW + (P0/3)*4 + (P0%3)] = pkbf(stg[k].x, stg[k].y);
            dst[mb*ROWDW + (P1/3)*4 + (P1%3)] = pkbf(stg[k].z, stg[k].w);
        }
    };

    load_ch(0); write_buf(0);
    uint4 xw = *reinterpret_cast<const uint4*>(myx + m*ROWDW);

    const bool is_g0 = (gq==0), is_g1 = (gq==1);

    unsigned B0 = is_g0 ? xw.x : 0u;
    unsigned B1 = is_g0 ? xw.y : 0u;
    unsigned B2 = is_g0 ? xw.z : 0u;
    unsigned B3 = 0u;
    float c0=0.f, c1=0.f, c2=0.f;
    float ht0=0.f, ht1=0.f, ht2=0.f;

    #pragma unroll 1
    for (int ch=0; ch<NCH; ++ch){
        const int cur = ch & 1;
        if (ch+1 < NCH) load_ch(ch+1);
        const unsigned* abase = myx + cur*BUFDW + m*ROWDW;        // current buffer row
        const unsigned* bbase = myx + (cur^1)*BUFDW + m*ROWDW;    // next buffer row

        #pragma unroll
        for (int tt=0; tt<TC; ++tt){
            FragU Bf; Bf.u[0]=B0; Bf.u[1]=B1; Bf.u[2]=B2; Bf.u[3]=B3;
            f32x4 a0 = __builtin_amdgcn_mfma_f32_16x16x32_bf16(wf[0].v, Bf.v, bias[0], 0,0,0);
            f32x4 a1 = __builtin_amdgcn_mfma_f32_16x16x32_bf16(wf[1].v, Bf.v, bias[1], 0,0,0);
            f32x4 a2 = __builtin_amdgcn_mfma_f32_16x16x32_bf16(wf[2].v, Bf.v, bias[2], 0,0,0);

            // next step's x words early (lgkm wait hides under the cell chains)
            uint4 xwn;
            if (tt < 15) xwn = *reinterpret_cast<const uint4*>(abase + (tt+1)*4);
            else         xwn = *reinterpret_cast<const uint4*>(bbase);   // stale at last chunk: unused

            cell(a0, c0, ht0);
            cell(a1, c1, ht1);
            cell(a2, c2, ht2);

            if (tt==14 && ch+1<NCH) write_buf(cur^1);   // stage next chunk before its first read

            // routing: pkA is every group's local word; one permlane swap moves
            // g3's ht2 (=h7) to g1 for the (h6,h7) word. No LDS ops.
            const unsigned pkA = pkbf(ht0, ht1);
            const unsigned pkB = pkbf(ht2, __uint_as_float(swap_hi32(ht2)));

            B0 = is_g0 ? xwn.x : pkA;
            B1 = is_g0 ? xwn.y : (is_g1 ? pkB : 0u);
            B2 = is_g0 ? xwn.z : 0u;
            B3 = is_g0 ? pkA   : 0u;
        }
    }

    // ---- final FC + sigmoid ----
    {
        const int ua = unit_of(gq,0);            hfin[wv][m][ua] = ht0;
        const int ub = unit_of(gq,1);            hfin[wv][m][ub] = ht1;
        const int uc = unit_of(gq,2); if (uc>=0) hfin[wv][m][uc] = ht2;
    }
    __syncthreads();
    if (l < 32){
        const int j = l >> 4, mm = l & 15;
        float a = bfc[j];
        #pragma unroll
        for (int u=0; u<10; ++u) a = fmaf(Wfc[j*10+u], hfin[wv][mm][u], a);
        out[(size_t)(blockIdx.x*64 + wv*16 + mm)*2 + j] = sigm(a);
    }
}

extern "C" void kernel_launch(void* const* d_in, const int* in_sizes, int n_in,
                              void* d_out, int out_size, void* d_ws, size_t ws_size,
                              hipStream_t stream) {
    const float* x   = (const float*)d_in[0];
    const float* Wih = (const float*)d_in[1];
    const float* Whh = (const float*)d_in[2];
    const float* bih = (const float*)d_in[3];
    const float* bhh = (const float*)d_in[4];
    const float* Wfc = (const float*)d_in[5];
    const float* bfc = (const float*)d_in[6];
    float* out = (float*)d_out;

    dim3 grid(16384 / 64);    // 256 blocks x 4 waves = 1024 waves -> 1/SIMD, 16 batches/wave
    dim3 block(256);
    Model_88459146428723_kernel<<<grid, block, 0, stream>>>(x, Wih, Whh, bih, bhh, Wfc, bfc, out);
}

// Round 13
// 167.876 us; speedup vs baseline: 1.5480x; 1.0748x over previous
//
#include <hip/hip_runtime.h>

typedef float f32x4  __attribute__((ext_vector_type(4)));
typedef short bf16x8 __attribute__((ext_vector_type(8)));

#define SEQT 512
#define TC   16
#define NCH  (SEQT/TC)
#define ROWDW 68              // dwords per batch-row per buffer (16 steps * 4 + 4 pad)
#define BUFDW (16*ROWDW)

#define FEXP2(v) __builtin_amdgcn_exp2f(v)
#define FRCP(v)  __builtin_amdgcn_rcpf(v)
__device__ __forceinline__ unsigned pkbf(float a, float b){ unsigned r; asm("v_cvt_pk_bf16_f32 %0, %1, %2":"=v"(r):"v"(a),"v"(b)); return r; }
__device__ __forceinline__ float sigm (float s){ return FRCP(1.0f + FEXP2(s * -1.4426950408889634f)); }

// lanes<32 receive lane+32's value of v (hardened: distinct regs guaranteed)
__device__ __forceinline__ unsigned swap_hi32(float v){
    unsigned dst, src;
    asm("v_mov_b32 %0, %2\n\t"
        "v_mov_b32 %1, %2\n\t"
        "v_permlane32_swap_b32 %0, %1"
        : "=&v"(dst), "=&v"(src)
        : "v"(__float_as_uint(v)));
    return src;
}

union FragU { unsigned u[4]; bf16x8 v; uint4 q; };

// Unit-to-cell map (cell = lane-group cg, tile t):
//   g0:{u0,u1,-}  g1:{u4,u5,u6}  g2:{u2,u3,-}  g3:{u9,u8,u7}
__device__ __forceinline__ int unit_of(int cg, int t){
    if (t==0) return cg==0 ? 0 : cg==1 ? 4 : cg==2 ? 2 : 9;
    if (t==1) return cg==0 ? 1 : cg==1 ? 5 : cg==2 ? 3 : 8;
    return      cg==0 ? -1 : cg==1 ? 6 : cg==2 ? -1 : 7;
}
// K-slot -> z-component (z = [x0..x5, h0..h9]); -1 = zero padding.
__device__ __forceinline__ int zslot(int k){
    if (k < 6)  return k;
    if (k == 6) return 6;
    if (k == 7) return 7;
    if (k == 8) return 10;
    if (k == 9) return 11;
    if (k == 10) return 12;
    if (k == 11) return 13;
    if (k == 16) return 8;
    if (k == 17) return 9;
    if (k == 24) return 15;
    if (k == 25) return 14;
    return -1;
}

// LSTM cell: R9's 7-trans gate structure (shared r for sigma(f) and i*g;
// separate off-path rcp for sigma(o)) + Pade(7,6) tanh on the c->h tail
// (replaces exp+rcp serial pair ~165cy with x2->3fma->rcp ~105cy; clamp +-5
// err 9e-5, validated by R12's pass at absmax 3.9e-3).
__device__ __forceinline__ void cell(const f32x4 a, float& c, float& h){
    const float K1 = -1.4426950408889634f;   // -log2(e)
    const float K2 = -2.8853900817779268f;   // -2*log2(e)
    float Ei = FEXP2(a[0]*K1);
    float Ef = FEXP2(a[1]*K1);
    float Eg = FEXP2(a[2]*K2);
    float Eo = FEXP2(a[3]*K1);
    float P  = (1.0f+Ei)*(1.0f+Eg);
    float Q  = 1.0f+Ef;
    float r  = FRCP(P*Q);
    float ig = (1.0f-Eg)*Q*r;        // sigma(i)*tanh(g)
    float sf = P*r;                  // sigma(f)
    float so = FRCP(1.0f+Eo);        // sigma(o) — off the c critical path
    c = fmaf(sf, c, ig);
    // tanh(c) via clamped Pade(7,6): cc*num/den
    float cc  = fminf(fmaxf(c, -5.0f), 5.0f);
    float x2  = cc*cc;
    float num = fmaf(x2, fmaf(x2, (x2+378.0f), 17325.0f), 135135.0f);
    float den = fmaf(x2, fmaf(x2, fmaf(x2, 28.0f, 3150.0f), 62370.0f), 135135.0f);
    h = (so * (cc*num)) * FRCP(den); // so*(cc*num) overlaps den's rcp latency
}

__global__ __launch_bounds__(256)
__attribute__((amdgpu_waves_per_eu(1, 1)))
void Model_88459146428723_kernel(const float* __restrict__ x,
                                 const float* __restrict__ Wih,
                                 const float* __restrict__ Whh,
                                 const float* __restrict__ bih,
                                 const float* __restrict__ bhh,
                                 const float* __restrict__ Wfc,
                                 const float* __restrict__ bfc,
                                 float* __restrict__ out)
{
    __shared__ unsigned xbf[4][2*BUFDW];     // per-wave private double-buffered x
    __shared__ float hfin[4][16][12];

    const int tid = threadIdx.x;
    const int wv = tid >> 6, l = tid & 63, m = l & 15, gq = l >> 4;

    // ---- A fragments: lane holds A-row (l&15), k = 8*(l>>4)+j ----
    FragU wf[3];
    #pragma unroll
    for (int t=0; t<3; ++t){
        const int u  = unit_of(m>>2, t);
        const int gt = m & 3;
        float av[8];
        #pragma unroll
        for (int j=0; j<8; ++j){
            const int z = zslot(8*gq + j);
            float v = 0.0f;
            if (u >= 0 && z >= 0){
                const int row = gt*10 + u;
                v = (z < 6) ? Wih[row*6 + z] : Whh[row*10 + (z-6)];
            }
            av[j] = v;
        }
        #pragma unroll
        for (int w=0; w<4; ++w) wf[t].u[w] = pkbf(av[2*w], av[2*w+1]);
    }
    // ---- bias as MFMA C-seed ----
    f32x4 bias[3];
    #pragma unroll
    for (int t=0; t<3; ++t){
        const int u = unit_of(gq, t);
        #pragma unroll
        for (int jD=0; jD<4; ++jD)
            bias[t][jD] = (u>=0) ? (bih[jD*10+u] + bhh[jD*10+u]) : 0.0f;
    }

    // ---- x staging: global f32 -> LDS bf16-pair words ----
    const float* xwb = x + (size_t)(blockIdx.x*64 + wv*16) * (SEQT*6);
    unsigned* myx = &xbf[wv][0];
    float4 stg[6];

    auto load_ch = [&](int ch){
        #pragma unroll
        for (int k=0; k<6; ++k){
            const int f = l + 64*k, mb = f/24, c4 = f%24;
            stg[k] = *reinterpret_cast<const float4*>(xwb + (size_t)mb*(SEQT*6) + ch*(TC*6) + c4*4);
        }
    };
    auto write_buf = [&](int buf){
        unsigned* dst = myx + buf*BUFDW;
        #pragma unroll
        for (int k=0; k<6; ++k){
            const int f = l + 64*k, mb = f/24, c4 = f%24;
            const int P0 = 2*c4, P1 = P0+1;
            dst[mb*ROWDW + (P0/3)*4 + (P0%3)] = pkbf(stg[k].x, stg[k].y);
            dst[mb*ROWDW + (P1/3)*4 + (P1%3)] = pkbf(stg[k].z, stg[k].w);
        }
    };

    load_ch(0); write_buf(0);
    uint4 xw = *reinterpret_cast<const uint4*>(myx + m*ROWDW);

    const bool is_g0 = (gq==0), is_g1 = (gq==1);

    unsigned B0 = is_g0 ? xw.x : 0u;
    unsigned B1 = is_g0 ? xw.y : 0u;
    unsigned B2 = is_g0 ? xw.z : 0u;
    unsigned B3 = 0u;
    float c0=0.f, c1=0.f, c2=0.f;
    float ht0=0.f, ht1=0.f, ht2=0.f;

    #pragma unroll 1
    for (int ch=0; ch<NCH; ++ch){
        const int cur = ch & 1;
        if (ch+1 < NCH) load_ch(ch+1);
        const unsigned* abase = myx + cur*BUFDW + m*ROWDW;        // current buffer row
        const unsigned* bbase = myx + (cur^1)*BUFDW + m*ROWDW;    // next buffer row

        #pragma unroll
        for (int tt=0; tt<TC; ++tt){
            FragU Bf; Bf.u[0]=B0; Bf.u[1]=B1; Bf.u[2]=B2; Bf.u[3]=B3;
            f32x4 a0 = __builtin_amdgcn_mfma_f32_16x16x32_bf16(wf[0].v, Bf.v, bias[0], 0,0,0);
            f32x4 a1 = __builtin_amdgcn_mfma_f32_16x16x32_bf16(wf[1].v, Bf.v, bias[1], 0,0,0);
            f32x4 a2 = __builtin_amdgcn_mfma_f32_16x16x32_bf16(wf[2].v, Bf.v, bias[2], 0,0,0);

            // next step's x words early (lgkm wait hides under the cell chains)
            uint4 xwn;
            if (tt < 15) xwn = *reinterpret_cast<const uint4*>(abase + (tt+1)*4);
            else         xwn = *reinterpret_cast<const uint4*>(bbase);   // stale at last chunk: unused

            cell(a0, c0, ht0);
            cell(a1, c1, ht1);
            cell(a2, c2, ht2);

            if (tt==14 && ch+1<NCH) write_buf(cur^1);   // stage next chunk before its first read

            // routing: pkA is every group's local word; one permlane swap moves
            // g3's ht2 (=h7) to g1 for the (h6,h7) word. No LDS ops.
            const unsigned pkA = pkbf(ht0, ht1);
            const unsigned pkB = pkbf(ht2, __uint_as_float(swap_hi32(ht2)));

            B0 = is_g0 ? xwn.x : pkA;
            B1 = is_g0 ? xwn.y : (is_g1 ? pkB : 0u);
            B2 = is_g0 ? xwn.z : 0u;
            B3 = is_g0 ? pkA   : 0u;
        }
    }

    // ---- final FC + sigmoid ----
    {
        const int ua = unit_of(gq,0);            hfin[wv][m][ua] = ht0;
        const int ub = unit_of(gq,1);            hfin[wv][m][ub] = ht1;
        const int uc = unit_of(gq,2); if (uc>=0) hfin[wv][m][uc] = ht2;
    }
    __syncthreads();
    if (l < 32){
        const int j = l >> 4, mm = l & 15;
        float a = bfc[j];
        #pragma unroll
        for (int u=0; u<10; ++u) a = fmaf(Wfc[j*10+u], hfin[wv][mm][u], a);
        out[(size_t)(blockIdx.x*64 + wv*16 + mm)*2 + j] = sigm(a);
    }
}

extern "C" void kernel_launch(void* const* d_in, const int* in_sizes, int n_in,
                              void* d_out, int out_size, void* d_ws, size_t ws_size,
                              hipStream_t stream) {
    const float* x   = (const float*)d_in[0];
    const float* Wih = (const float*)d_in[1];
    const float* Whh = (const float*)d_in[2];
    const float* bih = (const float*)d_in[3];
    const float* bhh = (const float*)d_in[4];
    const float* Wfc = (const float*)d_in[5];
    const float* bfc = (const float*)d_in[6];
    float* out = (float*)d_out;

    dim3 grid(16384 / 64);    // 256 blocks x 4 waves = 1024 waves -> 1/SIMD, 16 batches/wave
    dim3 block(256);
    Model_88459146428723_kernel<<<grid, block, 0, stream>>>(x, Wih, Whh, bih, bhh, Wfc, bfc, out);
}

// Round 14
// 151.579 us; speedup vs baseline: 1.7144x; 1.1075x over previous
//
#include <hip/hip_runtime.h>

typedef float f32x4  __attribute__((ext_vector_type(4)));
typedef short bf16x8 __attribute__((ext_vector_type(8)));

#define SEQT 512
#define TC   16
#define NCH  (SEQT/TC)
#define ROWDW 68              // dwords per batch-row per buffer (16 steps * 4 + 4 pad)
#define BUFDW (16*ROWDW)

#define FEXP2(v) __builtin_amdgcn_exp2f(v)
#define FRCP(v)  __builtin_amdgcn_rcpf(v)
__device__ __forceinline__ unsigned pkbf(float a, float b){ unsigned r; asm("v_cvt_pk_bf16_f32 %0, %1, %2":"=v"(r):"v"(a),"v"(b)); return r; }
__device__ __forceinline__ float sigm (float s){ return FRCP(1.0f + FEXP2(s * -1.4426950408889634f)); }

// lanes<32 receive lane+32's value of v (hardened: distinct regs guaranteed;
// R10's "+v","+v" same-value form could coalesce into a self-swap -> NaN)
__device__ __forceinline__ unsigned swap_hi32(float v){
    unsigned dst, src;
    asm("v_mov_b32 %0, %2\n\t"
        "v_mov_b32 %1, %2\n\t"
        "v_permlane32_swap_b32 %0, %1"
        : "=&v"(dst), "=&v"(src)
        : "v"(__float_as_uint(v)));
    return src;
}

union FragU { unsigned u[4]; bf16x8 v; uint4 q; };

// Unit-to-cell map (cell = lane-group cg, tile t):
//   g0:{u0,u1,-}  g1:{u4,u5,u6}  g2:{u2,u3,-}  g3:{u9,u8,u7}
__device__ __forceinline__ int unit_of(int cg, int t){
    if (t==0) return cg==0 ? 0 : cg==1 ? 4 : cg==2 ? 2 : 9;
    if (t==1) return cg==0 ? 1 : cg==1 ? 5 : cg==2 ? 3 : 8;
    return      cg==0 ? -1 : cg==1 ? 6 : cg==2 ? -1 : 7;
}
// K-slot -> z-component (z = [x0..x5, h0..h9]); -1 = zero padding.
__device__ __forceinline__ int zslot(int k){
    if (k < 6)  return k;
    if (k == 6) return 6;
    if (k == 7) return 7;
    if (k == 8) return 10;
    if (k == 9) return 11;
    if (k == 10) return 12;
    if (k == 11) return 13;
    if (k == 16) return 8;
    if (k == 17) return 9;
    if (k == 24) return 15;
    if (k == 25) return 14;
    return -1;
}

// R9's measured-optimal cell: 7 trans (5 exp + 2 rcp), sigma(o) merged into
// the output rcp. P=(1+Ei)(1+Eg), Q=1+Ef, r=rcp(PQ): sf=P*r, i*g=(1-Eg)Q*r;
// h = o*tanh(c) = (1-Ec)/[(1+Eo)(1+Ec)].
__device__ __forceinline__ void cell(const f32x4 a, float& c, float& h){
    const float K1 = -1.4426950408889634f;   // -log2(e)
    const float K2 = -2.8853900817779268f;   // -2*log2(e)
    float Ei = FEXP2(a[0]*K1);
    float Ef = FEXP2(a[1]*K1);
    float Eg = FEXP2(a[2]*K2);
    float Eo = FEXP2(a[3]*K1);
    float P  = (1.0f+Ei)*(1.0f+Eg);
    float Q  = 1.0f+Ef;
    float r  = FRCP(P*Q);
    float ig = (1.0f-Eg)*Q*r;
    float sf = P*r;
    c = fmaf(sf, c, ig);
    float Ec  = FEXP2(c*K2);
    float roc = FRCP((1.0f+Eo)*(1.0f+Ec));
    h = (1.0f-Ec)*roc;
}

__global__ __launch_bounds__(256)
__attribute__((amdgpu_waves_per_eu(1, 1)))
void Model_88459146428723_kernel(const float* __restrict__ x,
                                 const float* __restrict__ Wih,
                                 const float* __restrict__ Whh,
                                 const float* __restrict__ bih,
                                 const float* __restrict__ bhh,
                                 const float* __restrict__ Wfc,
                                 const float* __restrict__ bfc,
                                 float* __restrict__ out)
{
    __shared__ unsigned xbf[4][2*BUFDW];     // per-wave private double-buffered x
    __shared__ float hfin[4][16][12];

    const int tid = threadIdx.x;
    const int wv = tid >> 6, l = tid & 63, m = l & 15, gq = l >> 4;

    // ---- A fragments: lane holds A-row (l&15), k = 8*(l>>4)+j ----
    FragU wf[3];
    #pragma unroll
    for (int t=0; t<3; ++t){
        const int u  = unit_of(m>>2, t);
        const int gt = m & 3;
        float av[8];
        #pragma unroll
        for (int j=0; j<8; ++j){
            const int z = zslot(8*gq + j);
            float v = 0.0f;
            if (u >= 0 && z >= 0){
                const int row = gt*10 + u;
                v = (z < 6) ? Wih[row*6 + z] : Whh[row*10 + (z-6)];
            }
            av[j] = v;
        }
        #pragma unroll
        for (int w=0; w<4; ++w) wf[t].u[w] = pkbf(av[2*w], av[2*w+1]);
    }
    // ---- bias as MFMA C-seed ----
    f32x4 bias[3];
    #pragma unroll
    for (int t=0; t<3; ++t){
        const int u = unit_of(gq, t);
        #pragma unroll
        for (int jD=0; jD<4; ++jD)
            bias[t][jD] = (u>=0) ? (bih[jD*10+u] + bhh[jD*10+u]) : 0.0f;
    }

    // ---- x staging: global f32 -> LDS bf16-pair words ----
    const float* xwb = x + (size_t)(blockIdx.x*64 + wv*16) * (SEQT*6);
    unsigned* myx = &xbf[wv][0];
    float4 stg[6];

    auto load_ch = [&](int ch){
        #pragma unroll
        for (int k=0; k<6; ++k){
            const int f = l + 64*k, mb = f/24, c4 = f%24;
            stg[k] = *reinterpret_cast<const float4*>(xwb + (size_t)mb*(SEQT*6) + ch*(TC*6) + c4*4);
        }
    };
    auto write_buf = [&](int buf){
        unsigned* dst = myx + buf*BUFDW;
        #pragma unroll
        for (int k=0; k<6; ++k){
            const int f = l + 64*k, mb = f/24, c4 = f%24;
            const int P0 = 2*c4, P1 = P0+1;
            dst[mb*ROWDW + (P0/3)*4 + (P0%3)] = pkbf(stg[k].x, stg[k].y);
            dst[mb*ROWDW + (P1/3)*4 + (P1%3)] = pkbf(stg[k].z, stg[k].w);
        }
    };

    load_ch(0); write_buf(0);
    uint4 xw = *reinterpret_cast<const uint4*>(myx + m*ROWDW);

    const bool is_g0 = (gq==0), is_g1 = (gq==1);

    unsigned B0 = is_g0 ? xw.x : 0u;
    unsigned B1 = is_g0 ? xw.y : 0u;
    unsigned B2 = is_g0 ? xw.z : 0u;
    unsigned B3 = 0u;
    float c0=0.f, c1=0.f, c2=0.f;
    float ht0=0.f, ht1=0.f, ht2=0.f;

    #pragma unroll 1
    for (int ch=0; ch<NCH; ++ch){
        const int cur = ch & 1;
        if (ch+1 < NCH) load_ch(ch+1);
        const unsigned* abase = myx + cur*BUFDW + m*ROWDW;        // current buffer row
        const unsigned* bbase = myx + (cur^1)*BUFDW + m*ROWDW;    // next buffer row

        #pragma unroll
        for (int tt=0; tt<TC; ++tt){
            FragU Bf; Bf.u[0]=B0; Bf.u[1]=B1; Bf.u[2]=B2; Bf.u[3]=B3;
            f32x4 a0 = __builtin_amdgcn_mfma_f32_16x16x32_bf16(wf[0].v, Bf.v, bias[0], 0,0,0);
            f32x4 a1 = __builtin_amdgcn_mfma_f32_16x16x32_bf16(wf[1].v, Bf.v, bias[1], 0,0,0);
            f32x4 a2 = __builtin_amdgcn_mfma_f32_16x16x32_bf16(wf[2].v, Bf.v, bias[2], 0,0,0);

            // next step's x words early (lgkm wait hides under the cell chains)
            uint4 xwn;
            if (tt < 15) xwn = *reinterpret_cast<const uint4*>(abase + (tt+1)*4);
            else         xwn = *reinterpret_cast<const uint4*>(bbase);   // stale at last chunk: unused

            // t2 cell first: its h feeds the cross-lane swap -> issue the
            // permlane early so its latency hides under cells a0/a1
            cell(a2, c2, ht2);
            const unsigned sw2 = swap_hi32(ht2);
            cell(a0, c0, ht0);
            cell(a1, c1, ht1);

            if (tt==14 && ch+1<NCH) write_buf(cur^1);   // stage next chunk before its first read

            // routing: pkA is every group's local word; swap moved g3's ht2
            // (=h7) to g1 for the (h6,h7) word. No LDS ops.
            const unsigned pkA = pkbf(ht0, ht1);
            const unsigned pkB = pkbf(ht2, __uint_as_float(sw2));

            B0 = is_g0 ? xwn.x : pkA;
            B1 = is_g0 ? xwn.y : (is_g1 ? pkB : 0u);
            B2 = is_g0 ? xwn.z : 0u;
            B3 = is_g0 ? pkA   : 0u;
        }
    }

    // ---- final FC + sigmoid ----
    {
        const int ua = unit_of(gq,0);            hfin[wv][m][ua] = ht0;
        const int ub = unit_of(gq,1);            hfin[wv][m][ub] = ht1;
        const int uc = unit_of(gq,2); if (uc>=0) hfin[wv][m][uc] = ht2;
    }
    __syncthreads();
    if (l < 32){
        const int j = l >> 4, mm = l & 15;
        float a = bfc[j];
        #pragma unroll
        for (int u=0; u<10; ++u) a = fmaf(Wfc[j*10+u], hfin[wv][mm][u], a);
        out[(size_t)(blockIdx.x*64 + wv*16 + mm)*2 + j] = sigm(a);
    }
}

extern "C" void kernel_launch(void* const* d_in, const int* in_sizes, int n_in,
                              void* d_out, int out_size, void* d_ws, size_t ws_size,
                              hipStream_t stream) {
    const float* x   = (const float*)d_in[0];
    const float* Wih = (const float*)d_in[1];
    const float* Whh = (const float*)d_in[2];
    const float* bih = (const float*)d_in[3];
    const float* bhh = (const float*)d_in[4];
    const float* Wfc = (const float*)d_in[5];
    const float* bfc = (const float*)d_in[6];
    float* out = (float*)d_out;

    dim3 grid(16384 / 64);    // 256 blocks x 4 waves = 1024 waves -> 1/SIMD, 16 batches/wave
    dim3 block(256);
    Model_88459146428723_kernel<<<grid, block, 0, stream>>>(x, Wih, Whh, bih, bhh, Wfc, bfc, out);
}